// Round 4
// baseline (417.732 us; speedup 1.0000x reference)
//
#include <hip/hip_runtime.h>

typedef _Float16 f16;
typedef _Float16 f16x8 __attribute__((ext_vector_type(8)));
typedef _Float16 f16x4 __attribute__((ext_vector_type(4)));
typedef float f32x4 __attribute__((ext_vector_type(4)));

constexpr int NB = 32, NS = 576, ND = 768, NG = 24;
constexpr int M_TOT = NB * NS;   // 18432
constexpr int N_TOT = 3 * ND;    // 2304

// ---------------- kernel 1: build W_allT (N_TOT x ND) f16 via LDS tile transpose ----------------
// 36 n-tiles x 12 k-tiles of 64x64. Coalesced reads, padded LDS, coalesced writes.
__global__ __launch_bounds__(256) void cast_w_t_kernel(const float* __restrict__ Wq,
                                                       const float* __restrict__ Wk,
                                                       const float* __restrict__ Wv,
                                                       f16* __restrict__ WT) {
  __shared__ float tile[64][65];
  int bt = blockIdx.x;                 // 0..431
  int ntile = bt / 12, ktile = bt % 12;
  const float* src = (ntile < 12) ? Wq : ((ntile < 24) ? Wk : Wv);
  int n0 = (ntile % 12) * 64, k0 = ktile * 64;
  int cc = threadIdx.x & 63, rr = threadIdx.x >> 6;
#pragma unroll
  for (int i = 0; i < 16; i++) {
    int k = rr + i * 4;
    tile[cc][k] = src[(size_t)(k0 + k) * ND + n0 + cc];   // lanes span n: coalesced
  }
  __syncthreads();
#pragma unroll
  for (int i = 0; i < 16; i++) {
    int n = rr + i * 4;
    WT[(size_t)(ntile * 64 + n) * ND + k0 + cc] = (f16)tile[n][cc];  // lanes span k: coalesced
  }
}

// ---------------- kernel 2: Wc partials (j-split x8, fp32 atomics into WcfT[64][768]) ----------
__global__ void wc_partial_kernel(const float* __restrict__ Wq, const float* __restrict__ Wk,
                                  const float* __restrict__ W1, float* __restrict__ WcfT) {
  int b = blockIdx.x;                  // 0..1535
  int rb = b % 192, jc = b / 192;
  int flat = rb * 256 + threadIdx.x;
  int r = flat >> 6, c = flat & 63;
  if (c >= 60) return;
  const float* wq = Wq + (size_t)r * ND;
  const float* wk = Wk + (size_t)r * ND;
  float acc = 0.f;
  int j0 = jc * 96;
  for (int j = j0; j < j0 + 96; j++)
    acc += wq[j] * W1[j * 60 + c] + wk[j] * W1[(ND + j) * 60 + c];
  atomicAdd(&WcfT[(size_t)c * ND + r], acc);
}

// ---------------- kernel 3: split WcfT -> f16 hi/lo; compute bc ----------------
__global__ void wc_split_kernel(const float* __restrict__ WcfT,
                                const float* __restrict__ bq, const float* __restrict__ bk,
                                const float* __restrict__ W1, const float* __restrict__ b1,
                                f16* __restrict__ WcT_hi, f16* __restrict__ WcT_lo,
                                float* __restrict__ bc) {
  if (blockIdx.x == 192) {
    int c = threadIdx.x;
    if (c < 60) {
      float acc = b1[c];
      for (int j = 0; j < ND; j++)
        acc += bq[j] * W1[j * 60 + c] + bk[j] * W1[(ND + j) * 60 + c];
      bc[c] = acc;
    }
    return;
  }
  int t = blockIdx.x * 256 + threadIdx.x;  // 0..49151 over [c][r]
  float v = WcfT[t];
  f16 h = (f16)v;
  WcT_hi[t] = h;
  WcT_lo[t] = (f16)(v - (float)h);
}

// ---------------- kernel 4: GEMM qkv = x_f16 @ [Wq|Wk|Wv]_f16 (unchanged) ----------------
__device__ __forceinline__ void async_copy16(const f16* g, f16* l) {
  __builtin_amdgcn_global_load_lds((const __attribute__((address_space(1))) void*)g,
                                   (__attribute__((address_space(3))) void*)l, 16, 0, 0);
}

__global__ __launch_bounds__(256) void gemm_kernel(const f16* __restrict__ A,   // M_TOT x 768
                                                   const f16* __restrict__ Bt,  // 2304 x 768
                                                   const float* __restrict__ bq,
                                                   const float* __restrict__ bk,
                                                   const float* __restrict__ bv,
                                                   f16* __restrict__ C) {       // M_TOT x 2304
  constexpr int BM = 128, BK = 32;
  __shared__ __align__(16) f16 sA[BM * BK];
  __shared__ __align__(16) f16 sB[BM * BK];

  int bm = blockIdx.x % (M_TOT / BM);
  int bn = blockIdx.x / (M_TOT / BM);
  int tid = threadIdx.x;
  int wave = tid >> 6, lane = tid & 63;
  int wm = (wave >> 1) * 64, wn = (wave & 1) * 64;
  int m0 = bm * BM, n0 = bn * BM;

  int srow = tid >> 2;
  int skc = (tid & 3) * 8;

  f32x4 acc[4][4];
#pragma unroll
  for (int i = 0; i < 4; i++)
#pragma unroll
    for (int j = 0; j < 4; j++) acc[i][j] = 0.f;

  int q = lane >> 4, r16 = lane & 15;

  for (int kk = 0; kk < ND; kk += BK) {
    async_copy16(A + (size_t)(m0 + srow) * ND + kk + skc, sA + tid * 8);
    async_copy16(A + (size_t)(m0 + 64 + srow) * ND + kk + skc, sA + 2048 + tid * 8);
    async_copy16(Bt + (size_t)(n0 + srow) * ND + kk + skc, sB + tid * 8);
    async_copy16(Bt + (size_t)(n0 + 64 + srow) * ND + kk + skc, sB + 2048 + tid * 8);
    __syncthreads();

    f16x8 aF[4], bF[4];
#pragma unroll
    for (int mt = 0; mt < 4; mt++)
      aF[mt] = *(const f16x8*)(sA + (wm + mt * 16 + r16) * BK + q * 8);
#pragma unroll
    for (int nt = 0; nt < 4; nt++)
      bF[nt] = *(const f16x8*)(sB + (wn + nt * 16 + r16) * BK + q * 8);
#pragma unroll
    for (int mt = 0; mt < 4; mt++)
#pragma unroll
      for (int nt = 0; nt < 4; nt++)
        acc[mt][nt] = __builtin_amdgcn_mfma_f32_16x16x32_f16(aF[mt], bF[nt], acc[mt][nt], 0, 0, 0);
    __syncthreads();
  }

#pragma unroll
  for (int nt = 0; nt < 4; nt++) {
    int gn = n0 + wn + nt * 16 + r16;
    float bias = (gn < ND) ? bq[gn] : ((gn < 2 * ND) ? bk[gn - ND] : bv[gn - 2 * ND]);
#pragma unroll
    for (int mt = 0; mt < 4; mt++) {
#pragma unroll
      for (int r = 0; r < 4; r++) {
        int gm = m0 + wm + mt * 16 + q * 4 + r;
        C[(size_t)gm * N_TOT + gn] = (f16)(acc[mt][nt][r] + bias);
      }
    }
  }
}

// ---------------- kernel 5: z1 = relu(x @ Wc + bc) via split-f16 MFMA; ALSO emits xb ----------
__global__ __launch_bounds__(256) void z1_mfma_kernel(const float* __restrict__ x,
                                                      const f16* __restrict__ WcT_hi,
                                                      const f16* __restrict__ WcT_lo,
                                                      const float* __restrict__ bc,
                                                      float* __restrict__ h1,
                                                      f16* __restrict__ xb) {
  int wave = threadIdx.x >> 6, lane = threadIdx.x & 63;
  int q = lane >> 4, r16 = lane & 15;
  int m0 = blockIdx.x * 64 + wave * 16;          // 288 blocks
  const float* xr = x + (size_t)(m0 + r16) * ND;

  f32x4 acc[4];
#pragma unroll
  for (int nf = 0; nf < 4; nf++) acc[nf] = 0.f;

  for (int kk = 0; kk < ND; kk += 32) {
    int ko = kk + q * 8;
    float4 v0 = *(const float4*)(xr + ko);
    float4 v1 = *(const float4*)(xr + ko + 4);
    f16x8 a_hi, a_lo;
    float xv[8] = {v0.x, v0.y, v0.z, v0.w, v1.x, v1.y, v1.z, v1.w};
#pragma unroll
    for (int j = 0; j < 8; j++) {
      f16 h = (f16)xv[j];
      a_hi[j] = h;
      a_lo[j] = (f16)(xv[j] - (float)h);
    }
    *(f16x8*)(xb + (size_t)(m0 + r16) * ND + ko) = a_hi;   // fused cast_x
    f16x8 b_hi[4], b_lo[4];
#pragma unroll
    for (int nf = 0; nf < 4; nf++) {
      size_t off = (size_t)(nf * 16 + r16) * ND + ko;
      b_hi[nf] = *(const f16x8*)(WcT_hi + off);
      b_lo[nf] = *(const f16x8*)(WcT_lo + off);
    }
#pragma unroll
    for (int nf = 0; nf < 4; nf++) {
      acc[nf] = __builtin_amdgcn_mfma_f32_16x16x32_f16(a_hi, b_hi[nf], acc[nf], 0, 0, 0);
      acc[nf] = __builtin_amdgcn_mfma_f32_16x16x32_f16(a_lo, b_hi[nf], acc[nf], 0, 0, 0);
      acc[nf] = __builtin_amdgcn_mfma_f32_16x16x32_f16(a_hi, b_lo[nf], acc[nf], 0, 0, 0);
    }
  }

#pragma unroll
  for (int nf = 0; nf < 4; nf++) {
    int col = nf * 16 + r16;
    if (col < 60) {
      float bcv = bc[col];
#pragma unroll
      for (int r = 0; r < 4; r++)
        h1[(size_t)(m0 + q * 4 + r) * 60 + col] = fmaxf(acc[nf][r] + bcv, 0.f);
    }
  }
}

// ---------------- kernel 6: layers 2,3 + tanh + coord scatter; wave-per-row ----------------
__global__ void mlp_tail_kernel(const float* __restrict__ h1, const float* __restrict__ W2,
                                const float* __restrict__ b2, const float* __restrict__ W3,
                                const float* __restrict__ b3, float* __restrict__ coords) {
  int m = (blockIdx.x * 256 + threadIdx.x) >> 6;   // row
  int lane = threadIdx.x & 63;
  int cl = (lane < 60) ? lane : 59;
  const float* h = h1 + (size_t)m * 60;
  float acc = b2[cl];
  for (int j = 0; j < 60; j++) acc = fmaf(h[j], W2[j * 60 + cl], acc);
  float h2 = fmaxf(acc, 0.f);
  float p0 = (lane < 60) ? h2 * W3[cl * 2 + 0] : 0.f;
  float p1 = (lane < 60) ? h2 * W3[cl * 2 + 1] : 0.f;
#pragma unroll
  for (int o = 32; o > 0; o >>= 1) { p0 += __shfl_down(p0, o); p1 += __shfl_down(p1, o); }
  if (lane == 0) {
    float s0 = tanhf(p0 + b3[0]);
    float s1 = tanhf(p1 + b3[1]);
    int b = m / NS, s = m % NS;
    float* cb = coords + (size_t)b * (2 * NS);
    cb[(s >> 1) * 2 + (s & 1)] = s0;
    cb[(288 + (s >> 1)) * 2 + (s & 1)] = s1;
  }
}

// ---------------- kernel 7: bilinear sample + score + sigmoid*value; 1 wave/point ------------
__global__ __launch_bounds__(64) void sample_kernel(const f16* __restrict__ qkv,
                                                    const float* __restrict__ coords,
                                                    float* __restrict__ out) {
  int blk = blockIdx.x;            // 0..18431
  int b = blk / NS, p = blk % NS;
  int t = threadIdx.x;             // 0..63; lane owns 12 contiguous channels

  float gx = coords[(size_t)b * (2 * NS) + p * 2 + 0];
  float gy = coords[(size_t)b * (2 * NS) + p * 2 + 1];
  float ix = ((gx + 1.f) * (float)NG - 1.f) * 0.5f;
  float iy = ((gy + 1.f) * (float)NG - 1.f) * 0.5f;
  float x0f = floorf(ix), y0f = floorf(iy);
  float wx1 = ix - x0f, wx0 = 1.f - wx1;
  float wy1 = iy - y0f, wy0 = 1.f - wy1;
  int x0 = (int)x0f, y0 = (int)y0f, x1 = x0 + 1, y1 = y0 + 1;
  bool vx0 = (x0 >= 0) & (x0 <= NG - 1), vx1 = (x1 >= 0) & (x1 <= NG - 1);
  bool vy0 = (y0 >= 0) & (y0 <= NG - 1), vy1 = (y1 >= 0) & (y1 <= NG - 1);
  int cx0 = min(max(x0, 0), NG - 1), cx1 = min(max(x1, 0), NG - 1);
  int cy0 = min(max(y0, 0), NG - 1), cy1 = min(max(y1, 0), NG - 1);
  float w00 = wx0 * wy0 * ((vx0 && vy0) ? 1.f : 0.f);
  float w10 = wx1 * wy0 * ((vx1 && vy0) ? 1.f : 0.f);
  float w01 = wx0 * wy1 * ((vx0 && vy1) ? 1.f : 0.f);
  float w11 = wx1 * wy1 * ((vx1 && vy1) ? 1.f : 0.f);

  size_t base = (size_t)b * NS;
  const f16* r00 = qkv + (base + cy0 * NG + cx0) * N_TOT;
  const f16* r10 = qkv + (base + cy0 * NG + cx1) * N_TOT;
  const f16* r01 = qkv + (base + cy1 * NG + cx0) * N_TOT;
  const f16* r11 = qkv + (base + cy1 * NG + cx1) * N_TOT;
  const f16* qr  = qkv + (base + p) * N_TOT;

  int d0 = t * 12;
  float partial = 0.f;
  float outv[12];
#pragma unroll
  for (int ch = 0; ch < 3; ch++) {
    int d = d0 + ch * 4;
    f16x4 k00 = *(const f16x4*)(r00 + ND + d);
    f16x4 k10 = *(const f16x4*)(r10 + ND + d);
    f16x4 k01 = *(const f16x4*)(r01 + ND + d);
    f16x4 k11 = *(const f16x4*)(r11 + ND + d);
    f16x4 v00 = *(const f16x4*)(r00 + 2 * ND + d);
    f16x4 v10 = *(const f16x4*)(r10 + 2 * ND + d);
    f16x4 v01 = *(const f16x4*)(r01 + 2 * ND + d);
    f16x4 v11 = *(const f16x4*)(r11 + 2 * ND + d);
    f16x4 qv  = *(const f16x4*)(qr + d);
#pragma unroll
    for (int j = 0; j < 4; j++) {
      float sk = w00 * (float)k00[j] + w10 * (float)k10[j]
               + w01 * (float)k01[j] + w11 * (float)k11[j];
      float sv = w00 * (float)v00[j] + w10 * (float)v10[j]
               + w01 * (float)v01[j] + w11 * (float)v11[j];
      partial = fmaf((float)qv[j], sk, partial);
      outv[ch * 4 + j] = sv;
    }
  }
#pragma unroll
  for (int o = 32; o > 0; o >>= 1) partial += __shfl_down(partial, o);
  float score = __shfl(partial, 0);
  float sig = 1.f / (1.f + expf(-0.01f * score));
  float* orow = out + (size_t)(base + p) * ND;
#pragma unroll
  for (int ch = 0; ch < 3; ch++) {
    float4 st;
    st.x = sig * outv[ch * 4 + 0]; st.y = sig * outv[ch * 4 + 1];
    st.z = sig * outv[ch * 4 + 2]; st.w = sig * outv[ch * 4 + 3];
    *(float4*)(orow + d0 + ch * 4) = st;
  }
}

extern "C" void kernel_launch(void* const* d_in, const int* in_sizes, int n_in,
                              void* d_out, int out_size, void* d_ws, size_t ws_size,
                              hipStream_t stream) {
  const float* x  = (const float*)d_in[0];
  const float* Wq = (const float*)d_in[2];
  const float* bq = (const float*)d_in[3];
  const float* Wk = (const float*)d_in[4];
  const float* bk = (const float*)d_in[5];
  const float* Wv = (const float*)d_in[6];
  const float* bv = (const float*)d_in[7];
  const float* W1 = (const float*)d_in[8];
  const float* b1 = (const float*)d_in[9];
  const float* W2 = (const float*)d_in[10];
  const float* b2 = (const float*)d_in[11];
  const float* W3 = (const float*)d_in[12];
  const float* b3 = (const float*)d_in[13];
  float* out = (float*)d_out;

  char* ws = (char*)d_ws;
  f16*   xb     = (f16*)(ws);                       // 28,311,552 (written by z1, read by gemm)
  f16*   WT     = (f16*)(ws + 28311552);            //  3,538,944
  f16*   qkv    = (f16*)(ws + 31850496);            // 84,934,656 (written by gemm)
  // pre-gemm scratch carved from the qkv region (dead once gemm writes):
  f16*   WcT_hi = (f16*)(ws + 31850496);            //     98,304
  f16*   WcT_lo = (f16*)(ws + 31948800);            //     98,304
  float* WcfT   = (float*)(ws + 32047104);          //    196,608
  float* bc     = (float*)(ws + 116969472);         //        256
  float* h1     = (float*)(ws + 116969728);         //  4,423,680
  float* coords = (float*)(ws + 121393408);         //    147,456 (total 121,540,864)

  cast_w_t_kernel<<<dim3(432), dim3(256), 0, stream>>>(Wq, Wk, Wv, WT);
  hipMemsetAsync(WcfT, 0, 64 * ND * sizeof(float), stream);
  wc_partial_kernel<<<dim3(1536), dim3(256), 0, stream>>>(Wq, Wk, W1, WcfT);
  wc_split_kernel<<<dim3(193), dim3(256), 0, stream>>>(WcfT, bq, bk, W1, b1, WcT_hi, WcT_lo, bc);
  z1_mfma_kernel<<<dim3(M_TOT / 64), dim3(256), 0, stream>>>(x, WcT_hi, WcT_lo, bc, h1, xb);
  gemm_kernel<<<dim3((M_TOT / 128) * (N_TOT / 128)), dim3(256), 0, stream>>>(xb, WT, bq, bk, bv, qkv);
  mlp_tail_kernel<<<dim3(M_TOT / 4), dim3(256), 0, stream>>>(h1, W2, b2, W3, b3, coords);
  sample_kernel<<<dim3(M_TOT), dim3(64), 0, stream>>>(qkv, coords, out);
  (void)in_sizes; (void)n_in; (void)out_size; (void)ws_size;
}

// Round 5
// 384.574 us; speedup vs baseline: 1.0862x; 1.0862x over previous
//
#include <hip/hip_runtime.h>

typedef _Float16 f16;
typedef _Float16 f16x8 __attribute__((ext_vector_type(8)));
typedef _Float16 f16x4 __attribute__((ext_vector_type(4)));
typedef float f32x4 __attribute__((ext_vector_type(4)));

constexpr int NB = 32, NS = 576, ND = 768, NG = 24;
constexpr int M_TOT = NB * NS;   // 18432
constexpr int N_TOT = 3 * ND;    // 2304

// ---------------- kernel 1: cast x (fp32 -> f16) ----------------
__global__ void cast_x_kernel(const float* __restrict__ x, f16* __restrict__ xb) {
  int i = (blockIdx.x * 256 + threadIdx.x) * 4;
  float4 v = *(const float4*)(x + i);
  f16x4 o;
  o.x = (f16)v.x; o.y = (f16)v.y; o.z = (f16)v.z; o.w = (f16)v.w;
  *(f16x4*)(xb + i) = o;
}

// ---------------- kernel 2: build W_allT (N_TOT x ND) f16 via LDS tile transpose ----------------
__global__ __launch_bounds__(256) void cast_w_t_kernel(const float* __restrict__ Wq,
                                                       const float* __restrict__ Wk,
                                                       const float* __restrict__ Wv,
                                                       f16* __restrict__ WT) {
  __shared__ float tile[64][65];
  int bt = blockIdx.x;                 // 0..431
  int ntile = bt / 12, ktile = bt % 12;
  const float* src = (ntile < 12) ? Wq : ((ntile < 24) ? Wk : Wv);
  int n0 = (ntile % 12) * 64, k0 = ktile * 64;
  int cc = threadIdx.x & 63, rr = threadIdx.x >> 6;
#pragma unroll
  for (int i = 0; i < 16; i++) {
    int k = rr + i * 4;
    tile[cc][k] = src[(size_t)(k0 + k) * ND + n0 + cc];
  }
  __syncthreads();
#pragma unroll
  for (int i = 0; i < 16; i++) {
    int n = rr + i * 4;
    WT[(size_t)(ntile * 64 + n) * ND + k0 + cc] = (f16)tile[n][cc];
  }
}

// ---------------- kernel 3: WcT hi/lo (f16 split of Wq@W1a + Wk@W1b), [64][768]; bc ----------
__global__ void wcT_kernel(const float* __restrict__ Wq, const float* __restrict__ Wk,
                           const float* __restrict__ bq, const float* __restrict__ bk,
                           const float* __restrict__ W1, const float* __restrict__ b1,
                           f16* __restrict__ WcT_hi, f16* __restrict__ WcT_lo,
                           float* __restrict__ bc) {
  if (blockIdx.x == 192) {
    int c = threadIdx.x;
    if (c < 60) {
      float acc = b1[c];
      for (int j = 0; j < ND; j++)
        acc += bq[j] * W1[j * 60 + c] + bk[j] * W1[(ND + j) * 60 + c];
      bc[c] = acc;
    }
    return;
  }
  int flat = blockIdx.x * 256 + threadIdx.x;   // 0..49151
  int r = flat >> 6, c = flat & 63;
  float acc = 0.f;
  if (c < 60) {
    const float* wq = Wq + (size_t)r * ND;
    const float* wk = Wk + (size_t)r * ND;
    for (int j = 0; j < ND; j++)
      acc += wq[j] * W1[j * 60 + c] + wk[j] * W1[(ND + j) * 60 + c];
  }
  f16 hi = (f16)acc;
  f16 lo = (f16)(acc - (float)hi);
  WcT_hi[(size_t)c * ND + r] = hi;
  WcT_lo[(size_t)c * ND + r] = lo;
}

// ---------------- kernel 4: GEMM qkv = x_f16 @ [Wq|Wk|Wv]_f16 ----------------
// XOR-swizzled LDS chunks (bank-conflict-free b128 frag reads) + C^T-form MFMA
// (operands swapped) so the epilogue stores f16x4 per (mt,nt).
__device__ __forceinline__ void async_copy16(const f16* g, f16* l) {
  __builtin_amdgcn_global_load_lds((const __attribute__((address_space(1))) void*)g,
                                   (__attribute__((address_space(3))) void*)l, 16, 0, 0);
}

__global__ __launch_bounds__(256) void gemm_kernel(const f16* __restrict__ A,   // M_TOT x 768
                                                   const f16* __restrict__ Bt,  // 2304 x 768
                                                   const float* __restrict__ bq,
                                                   const float* __restrict__ bk,
                                                   const float* __restrict__ bv,
                                                   f16* __restrict__ C) {       // M_TOT x 2304
  constexpr int BM = 128, BK = 32;
  __shared__ __align__(16) f16 sA[BM * BK];
  __shared__ __align__(16) f16 sB[BM * BK];

  int bm = blockIdx.x % (M_TOT / BM);
  int bn = blockIdx.x / (M_TOT / BM);
  int tid = threadIdx.x;
  int wave = tid >> 6, lane = tid & 63;
  int wm = (wave >> 1) * 64, wn = (wave & 1) * 64;
  int m0 = bm * BM, n0 = bn * BM;

  int srow = tid >> 2;
  int skc = ((tid & 3) ^ ((tid >> 3) & 3)) * 8;   // XOR-swizzled source chunk

  f32x4 acc[4][4];
#pragma unroll
  for (int i = 0; i < 4; i++)
#pragma unroll
    for (int j = 0; j < 4; j++) acc[i][j] = 0.f;

  int q = lane >> 4, r16 = lane & 15;
  int sw = (q ^ ((r16 >> 1) & 3)) * 8;            // swizzled frag slot (lane-only)

  for (int kk = 0; kk < ND; kk += BK) {
    async_copy16(A + (size_t)(m0 + srow) * ND + kk + skc, sA + tid * 8);
    async_copy16(A + (size_t)(m0 + 64 + srow) * ND + kk + skc, sA + 2048 + tid * 8);
    async_copy16(Bt + (size_t)(n0 + srow) * ND + kk + skc, sB + tid * 8);
    async_copy16(Bt + (size_t)(n0 + 64 + srow) * ND + kk + skc, sB + 2048 + tid * 8);
    __syncthreads();

    f16x8 aF[4], bF[4];
#pragma unroll
    for (int mt = 0; mt < 4; mt++)
      aF[mt] = *(const f16x8*)(sA + (wm + mt * 16 + r16) * BK + sw);
#pragma unroll
    for (int nt = 0; nt < 4; nt++)
      bF[nt] = *(const f16x8*)(sB + (wn + nt * 16 + r16) * BK + sw);
#pragma unroll
    for (int mt = 0; mt < 4; mt++)
#pragma unroll
      for (int nt = 0; nt < 4; nt++)   // swapped operands -> C^T register layout
        acc[mt][nt] = __builtin_amdgcn_mfma_f32_16x16x32_f16(bF[nt], aF[mt], acc[mt][nt], 0, 0, 0);
    __syncthreads();
  }

#pragma unroll
  for (int mt = 0; mt < 4; mt++) {
    int gm = m0 + wm + mt * 16 + r16;
#pragma unroll
    for (int nt = 0; nt < 4; nt++) {
      int gn0 = n0 + wn + nt * 16 + q * 4;
      const float* bp = (gn0 < ND) ? (bq + gn0)
                      : ((gn0 < 2 * ND) ? (bk + gn0 - ND) : (bv + gn0 - 2 * ND));
      float4 bias = *(const float4*)bp;
      f16x4 o;
      o[0] = (f16)(acc[mt][nt][0] + bias.x);
      o[1] = (f16)(acc[mt][nt][1] + bias.y);
      o[2] = (f16)(acc[mt][nt][2] + bias.z);
      o[3] = (f16)(acc[mt][nt][3] + bias.w);
      *(f16x4*)(C + (size_t)gm * N_TOT + gn0) = o;
    }
  }
}

// ---------------- kernel 5: z1 = relu(x @ Wc + bc), split-f16 MFMA, K-split x2 ----------------
// 576 blocks x 4 waves: wave = (rowgroup rg = w&1, K-half kh = w>>1). LDS combine.
__global__ __launch_bounds__(256) void z1_mfma_kernel(const float* __restrict__ x,
                                                      const f16* __restrict__ WcT_hi,
                                                      const f16* __restrict__ WcT_lo,
                                                      const float* __restrict__ bc,
                                                      float* __restrict__ h1) {
  __shared__ float red[2][16][64];   // [rg][reg-idx][lane]
  int wave = threadIdx.x >> 6, lane = threadIdx.x & 63;
  int q = lane >> 4, r16 = lane & 15;
  int rg = wave & 1, kh = wave >> 1;
  int m0 = blockIdx.x * 32 + rg * 16;
  int k0 = kh * 384;
  const float* xr = x + (size_t)(m0 + r16) * ND + k0;

  f32x4 acc[4];
#pragma unroll
  for (int nf = 0; nf < 4; nf++) acc[nf] = 0.f;

  for (int kk = 0; kk < 384; kk += 32) {
    int ko = kk + q * 8;
    float4 v0 = *(const float4*)(xr + ko);
    float4 v1 = *(const float4*)(xr + ko + 4);
    f16x8 a_hi, a_lo;
    float xv[8] = {v0.x, v0.y, v0.z, v0.w, v1.x, v1.y, v1.z, v1.w};
#pragma unroll
    for (int j = 0; j < 8; j++) {
      f16 h = (f16)xv[j];
      a_hi[j] = h;
      a_lo[j] = (f16)(xv[j] - (float)h);
    }
    f16x8 b_hi[4], b_lo[4];
#pragma unroll
    for (int nf = 0; nf < 4; nf++) {
      size_t off = (size_t)(nf * 16 + r16) * ND + k0 + ko;
      b_hi[nf] = *(const f16x8*)(WcT_hi + off);
      b_lo[nf] = *(const f16x8*)(WcT_lo + off);
    }
#pragma unroll
    for (int nf = 0; nf < 4; nf++) {
      acc[nf] = __builtin_amdgcn_mfma_f32_16x16x32_f16(a_hi, b_hi[nf], acc[nf], 0, 0, 0);
      acc[nf] = __builtin_amdgcn_mfma_f32_16x16x32_f16(a_lo, b_hi[nf], acc[nf], 0, 0, 0);
      acc[nf] = __builtin_amdgcn_mfma_f32_16x16x32_f16(a_hi, b_lo[nf], acc[nf], 0, 0, 0);
    }
  }

  if (kh == 1) {
#pragma unroll
    for (int nf = 0; nf < 4; nf++)
#pragma unroll
      for (int r = 0; r < 4; r++) red[rg][nf * 4 + r][lane] = acc[nf][r];
  }
  __syncthreads();
  if (kh == 0) {
#pragma unroll
    for (int nf = 0; nf < 4; nf++) {
      int col = nf * 16 + r16;
      if (col < 60) {
        float bcv = bc[col];
#pragma unroll
        for (int r = 0; r < 4; r++) {
          float v = acc[nf][r] + red[rg][nf * 4 + r][lane] + bcv;
          h1[(size_t)(m0 + q * 4 + r) * 60 + col] = fmaxf(v, 0.f);
        }
      }
    }
  }
}

// ---------------- kernel 6: layers 2,3 + tanh + coord scatter; wave-per-row ----------------
__global__ void mlp_tail_kernel(const float* __restrict__ h1, const float* __restrict__ W2,
                                const float* __restrict__ b2, const float* __restrict__ W3,
                                const float* __restrict__ b3, float* __restrict__ coords) {
  int m = (blockIdx.x * 256 + threadIdx.x) >> 6;   // row
  int lane = threadIdx.x & 63;
  int cl = (lane < 60) ? lane : 59;
  const float* h = h1 + (size_t)m * 60;
  float acc = b2[cl];
  for (int j = 0; j < 60; j++) acc = fmaf(h[j], W2[j * 60 + cl], acc);
  float h2 = fmaxf(acc, 0.f);
  float p0 = (lane < 60) ? h2 * W3[cl * 2 + 0] : 0.f;
  float p1 = (lane < 60) ? h2 * W3[cl * 2 + 1] : 0.f;
#pragma unroll
  for (int o = 32; o > 0; o >>= 1) { p0 += __shfl_down(p0, o); p1 += __shfl_down(p1, o); }
  if (lane == 0) {
    float s0 = tanhf(p0 + b3[0]);
    float s1 = tanhf(p1 + b3[1]);
    int b = m / NS, s = m % NS;
    float* cb = coords + (size_t)b * (2 * NS);
    cb[(s >> 1) * 2 + (s & 1)] = s0;
    cb[(288 + (s >> 1)) * 2 + (s & 1)] = s1;
  }
}

// ---------------- kernel 7: bilinear sample + score + sigmoid*value; 1 wave/point ------------
__global__ __launch_bounds__(64) void sample_kernel(const f16* __restrict__ qkv,
                                                    const float* __restrict__ coords,
                                                    float* __restrict__ out) {
  int blk = blockIdx.x;            // 0..18431
  int b = blk / NS, p = blk % NS;
  int t = threadIdx.x;             // lane owns 12 contiguous channels

  float gx = coords[(size_t)b * (2 * NS) + p * 2 + 0];
  float gy = coords[(size_t)b * (2 * NS) + p * 2 + 1];
  float ix = ((gx + 1.f) * (float)NG - 1.f) * 0.5f;
  float iy = ((gy + 1.f) * (float)NG - 1.f) * 0.5f;
  float x0f = floorf(ix), y0f = floorf(iy);
  float wx1 = ix - x0f, wx0 = 1.f - wx1;
  float wy1 = iy - y0f, wy0 = 1.f - wy1;
  int x0 = (int)x0f, y0 = (int)y0f, x1 = x0 + 1, y1 = y0 + 1;
  bool vx0 = (x0 >= 0) & (x0 <= NG - 1), vx1 = (x1 >= 0) & (x1 <= NG - 1);
  bool vy0 = (y0 >= 0) & (y0 <= NG - 1), vy1 = (y1 >= 0) & (y1 <= NG - 1);
  int cx0 = min(max(x0, 0), NG - 1), cx1 = min(max(x1, 0), NG - 1);
  int cy0 = min(max(y0, 0), NG - 1), cy1 = min(max(y1, 0), NG - 1);
  float w00 = wx0 * wy0 * ((vx0 && vy0) ? 1.f : 0.f);
  float w10 = wx1 * wy0 * ((vx1 && vy0) ? 1.f : 0.f);
  float w01 = wx0 * wy1 * ((vx0 && vy1) ? 1.f : 0.f);
  float w11 = wx1 * wy1 * ((vx1 && vy1) ? 1.f : 0.f);

  size_t base = (size_t)b * NS;
  const f16* r00 = qkv + (base + cy0 * NG + cx0) * N_TOT;
  const f16* r10 = qkv + (base + cy0 * NG + cx1) * N_TOT;
  const f16* r01 = qkv + (base + cy1 * NG + cx0) * N_TOT;
  const f16* r11 = qkv + (base + cy1 * NG + cx1) * N_TOT;
  const f16* qr  = qkv + (base + p) * N_TOT;

  int d0 = t * 12;
  float partial = 0.f;
  float outv[12];
#pragma unroll
  for (int ch = 0; ch < 3; ch++) {
    int d = d0 + ch * 4;
    f16x4 k00 = *(const f16x4*)(r00 + ND + d);
    f16x4 k10 = *(const f16x4*)(r10 + ND + d);
    f16x4 k01 = *(const f16x4*)(r01 + ND + d);
    f16x4 k11 = *(const f16x4*)(r11 + ND + d);
    f16x4 v00 = *(const f16x4*)(r00 + 2 * ND + d);
    f16x4 v10 = *(const f16x4*)(r10 + 2 * ND + d);
    f16x4 v01 = *(const f16x4*)(r01 + 2 * ND + d);
    f16x4 v11 = *(const f16x4*)(r11 + 2 * ND + d);
    f16x4 qv  = *(const f16x4*)(qr + d);
#pragma unroll
    for (int j = 0; j < 4; j++) {
      float sk = w00 * (float)k00[j] + w10 * (float)k10[j]
               + w01 * (float)k01[j] + w11 * (float)k11[j];
      float sv = w00 * (float)v00[j] + w10 * (float)v10[j]
               + w01 * (float)v01[j] + w11 * (float)v11[j];
      partial = fmaf((float)qv[j], sk, partial);
      outv[ch * 4 + j] = sv;
    }
  }
#pragma unroll
  for (int o = 32; o > 0; o >>= 1) partial += __shfl_down(partial, o);
  float score = __shfl(partial, 0);
  float sig = 1.f / (1.f + expf(-0.01f * score));
  float* orow = out + (size_t)(base + p) * ND;
#pragma unroll
  for (int ch = 0; ch < 3; ch++) {
    float4 st;
    st.x = sig * outv[ch * 4 + 0]; st.y = sig * outv[ch * 4 + 1];
    st.z = sig * outv[ch * 4 + 2]; st.w = sig * outv[ch * 4 + 3];
    *(float4*)(orow + d0 + ch * 4) = st;
  }
}

extern "C" void kernel_launch(void* const* d_in, const int* in_sizes, int n_in,
                              void* d_out, int out_size, void* d_ws, size_t ws_size,
                              hipStream_t stream) {
  const float* x  = (const float*)d_in[0];
  const float* Wq = (const float*)d_in[2];
  const float* bq = (const float*)d_in[3];
  const float* Wk = (const float*)d_in[4];
  const float* bk = (const float*)d_in[5];
  const float* Wv = (const float*)d_in[6];
  const float* bv = (const float*)d_in[7];
  const float* W1 = (const float*)d_in[8];
  const float* b1 = (const float*)d_in[9];
  const float* W2 = (const float*)d_in[10];
  const float* b2 = (const float*)d_in[11];
  const float* W3 = (const float*)d_in[12];
  const float* b3 = (const float*)d_in[13];
  float* out = (float*)d_out;

  char* ws = (char*)d_ws;
  f16*   xb     = (f16*)(ws);                       // 28,311,552
  f16*   WT     = (f16*)(ws + 28311552);            //  3,538,944
  f16*   qkv    = (f16*)(ws + 31850496);            // 84,934,656
  // pre-gemm scratch carved from qkv region (consumed by z1 BEFORE gemm writes qkv):
  f16*   WcT_hi = (f16*)(ws + 31850496);            //     98,304
  f16*   WcT_lo = (f16*)(ws + 31948800);            //     98,304
  float* bc     = (float*)(ws + 116969472);         //        256
  float* h1     = (float*)(ws + 116969728);         //  4,423,680
  float* coords = (float*)(ws + 121393408);         //    147,456 (total 121,540,864)

  cast_x_kernel<<<dim3(M_TOT * ND / 1024), dim3(256), 0, stream>>>(x, xb);
  cast_w_t_kernel<<<dim3(432), dim3(256), 0, stream>>>(Wq, Wk, Wv, WT);
  wcT_kernel<<<dim3(193), dim3(256), 0, stream>>>(Wq, Wk, bq, bk, W1, b1, WcT_hi, WcT_lo, bc);
  z1_mfma_kernel<<<dim3(M_TOT / 32), dim3(256), 0, stream>>>(x, WcT_hi, WcT_lo, bc, h1);
  gemm_kernel<<<dim3((M_TOT / 128) * (N_TOT / 128)), dim3(256), 0, stream>>>(xb, WT, bq, bk, bv, qkv);
  mlp_tail_kernel<<<dim3(M_TOT / 4), dim3(256), 0, stream>>>(h1, W2, b2, W3, b3, coords);
  sample_kernel<<<dim3(M_TOT), dim3(64), 0, stream>>>(qkv, coords, out);
  (void)in_sizes; (void)n_in; (void)out_size; (void)ws_size;
}

// Round 6
// 355.626 us; speedup vs baseline: 1.1746x; 1.0814x over previous
//
#include <hip/hip_runtime.h>

typedef _Float16 f16;
typedef _Float16 f16x8 __attribute__((ext_vector_type(8)));
typedef _Float16 f16x4 __attribute__((ext_vector_type(4)));
typedef float f32x4 __attribute__((ext_vector_type(4)));

constexpr int NB = 32, NS = 576, ND = 768, NG = 24;
constexpr int M_TOT = NB * NS;   // 18432
constexpr int N_TOT = 3 * ND;    // 2304

// ---------------- kernel 1: cast x (fp32 -> f16) ----------------
__global__ void cast_x_kernel(const float* __restrict__ x, f16* __restrict__ xb) {
  int i = (blockIdx.x * 256 + threadIdx.x) * 4;
  float4 v = *(const float4*)(x + i);
  f16x4 o;
  o.x = (f16)v.x; o.y = (f16)v.y; o.z = (f16)v.z; o.w = (f16)v.w;
  *(f16x4*)(xb + i) = o;
}

// ---------------- kernel 2: build W_allT (N_TOT x ND) f16 via LDS tile transpose ----------------
__global__ __launch_bounds__(256) void cast_w_t_kernel(const float* __restrict__ Wq,
                                                       const float* __restrict__ Wk,
                                                       const float* __restrict__ Wv,
                                                       f16* __restrict__ WT) {
  __shared__ float tile[64][65];
  int bt = blockIdx.x;                 // 0..431
  int ntile = bt / 12, ktile = bt % 12;
  const float* src = (ntile < 12) ? Wq : ((ntile < 24) ? Wk : Wv);
  int n0 = (ntile % 12) * 64, k0 = ktile * 64;
  int cc = threadIdx.x & 63, rr = threadIdx.x >> 6;
#pragma unroll
  for (int i = 0; i < 16; i++) {
    int k = rr + i * 4;
    tile[cc][k] = src[(size_t)(k0 + k) * ND + n0 + cc];
  }
  __syncthreads();
#pragma unroll
  for (int i = 0; i < 16; i++) {
    int n = rr + i * 4;
    WT[(size_t)(ntile * 64 + n) * ND + k0 + cc] = (f16)tile[n][cc];
  }
}

// ---------------- kernel 3: WcT hi/lo, j-split x4 per block; bc in block 768 ----------------
__global__ __launch_bounds__(256) void wcT_kernel(const float* __restrict__ Wq,
                                                  const float* __restrict__ Wk,
                                                  const float* __restrict__ bq,
                                                  const float* __restrict__ bk,
                                                  const float* __restrict__ W1,
                                                  const float* __restrict__ b1,
                                                  f16* __restrict__ WcT_hi,
                                                  f16* __restrict__ WcT_lo,
                                                  float* __restrict__ bc) {
  if (blockIdx.x == 768) {
    int c = threadIdx.x;
    if (c < 60) {
      float acc = b1[c];
      for (int j = 0; j < ND; j++)
        acc += bq[j] * W1[j * 60 + c] + bk[j] * W1[(ND + j) * 60 + c];
      bc[c] = acc;
    }
    return;
  }
  __shared__ float part[4][64];
  int r = blockIdx.x;                       // 0..767
  int wave = threadIdx.x >> 6, lane = threadIdx.x & 63;
  int c = (lane < 60) ? lane : 59;
  const float* wq = Wq + (size_t)r * ND;
  const float* wk = Wk + (size_t)r * ND;
  float acc = 0.f;
  int j0 = wave * 192;
  for (int j = j0; j < j0 + 192; j++)
    acc += wq[j] * W1[j * 60 + c] + wk[j] * W1[(ND + j) * 60 + c];
  part[wave][lane] = acc;
  __syncthreads();
  if (wave == 0 && lane < 60) {
    float v = part[0][lane] + part[1][lane] + part[2][lane] + part[3][lane];
    f16 hi = (f16)v;
    WcT_hi[(size_t)lane * ND + r] = hi;
    WcT_lo[(size_t)lane * ND + r] = (f16)(v - (float)hi);
  }
}

// ---------------- kernel 4: GEMM qkv = x_f16 @ [Wq|Wk|Wv]_f16, BK=64 ----------------
// XOR-swizzled LDS chunks (conflict-free b128 frag reads), C^T-form MFMA, f16x4 epilogue.
__device__ __forceinline__ void async_copy16(const f16* g, f16* l) {
  __builtin_amdgcn_global_load_lds((const __attribute__((address_space(1))) void*)g,
                                   (__attribute__((address_space(3))) void*)l, 16, 0, 0);
}

__global__ __launch_bounds__(256) void gemm_kernel(const f16* __restrict__ A,   // M_TOT x 768
                                                   const f16* __restrict__ Bt,  // 2304 x 768
                                                   const float* __restrict__ bq,
                                                   const float* __restrict__ bk,
                                                   const float* __restrict__ bv,
                                                   f16* __restrict__ C) {       // M_TOT x 2304
  constexpr int BM = 128, BK = 64;
  __shared__ __align__(16) f16 sA[BM * BK];   // 16 KB
  __shared__ __align__(16) f16 sB[BM * BK];   // 16 KB

  int bm = blockIdx.x % (M_TOT / BM);
  int bn = blockIdx.x / (M_TOT / BM);
  int tid = threadIdx.x;
  int wave = tid >> 6, lane = tid & 63;
  int wm = (wave >> 1) * 64, wn = (wave & 1) * 64;
  int m0 = bm * BM, n0 = bn * BM;

  int srow = tid >> 3;                          // 0..31
  int gchunk = ((tid & 7) ^ (srow & 7)) * 8;    // swizzled global chunk (elements)

  f32x4 acc[4][4];
#pragma unroll
  for (int i = 0; i < 4; i++)
#pragma unroll
    for (int j = 0; j < 4; j++) acc[i][j] = 0.f;

  int q = lane >> 4, r16 = lane & 15;

  for (int kk = 0; kk < ND; kk += BK) {
#pragma unroll
    for (int ps = 0; ps < 4; ps++) {
      async_copy16(A + (size_t)(m0 + ps * 32 + srow) * ND + kk + gchunk, sA + ps * 2048 + tid * 8);
      async_copy16(Bt + (size_t)(n0 + ps * 32 + srow) * ND + kk + gchunk, sB + ps * 2048 + tid * 8);
    }
    __syncthreads();

#pragma unroll
    for (int h = 0; h < 2; h++) {
      f16x8 aF[4], bF[4];
#pragma unroll
      for (int mt = 0; mt < 4; mt++) {
        int R = wm + mt * 16 + r16;
        aF[mt] = *(const f16x8*)(sA + R * 64 + (((h * 4 + q) ^ (R & 7)) * 8));
      }
#pragma unroll
      for (int nt = 0; nt < 4; nt++) {
        int R = wn + nt * 16 + r16;
        bF[nt] = *(const f16x8*)(sB + R * 64 + (((h * 4 + q) ^ (R & 7)) * 8));
      }
#pragma unroll
      for (int mt = 0; mt < 4; mt++)
#pragma unroll
        for (int nt = 0; nt < 4; nt++)   // swapped operands -> C^T register layout
          acc[mt][nt] = __builtin_amdgcn_mfma_f32_16x16x32_f16(bF[nt], aF[mt], acc[mt][nt], 0, 0, 0);
    }
    __syncthreads();
  }

#pragma unroll
  for (int mt = 0; mt < 4; mt++) {
    int gm = m0 + wm + mt * 16 + r16;
#pragma unroll
    for (int nt = 0; nt < 4; nt++) {
      int gn0 = n0 + wn + nt * 16 + q * 4;
      const float* bp = (gn0 < ND) ? (bq + gn0)
                      : ((gn0 < 2 * ND) ? (bk + gn0 - ND) : (bv + gn0 - 2 * ND));
      float4 bias = *(const float4*)bp;
      f16x4 o;
      o[0] = (f16)(acc[mt][nt][0] + bias.x);
      o[1] = (f16)(acc[mt][nt][1] + bias.y);
      o[2] = (f16)(acc[mt][nt][2] + bias.z);
      o[3] = (f16)(acc[mt][nt][3] + bias.w);
      *(f16x4*)(C + (size_t)gm * N_TOT + gn0) = o;
    }
  }
}

// ---------------- kernel 5: z1 = relu(x @ Wc + bc), split-f16 MFMA, K-split x4 ----------------
// 1152 blocks x 16 rows; 4 waves = 4 K-quarters (192 each); LDS combine in wave 0.
__global__ __launch_bounds__(256) void z1_mfma_kernel(const float* __restrict__ x,
                                                      const f16* __restrict__ WcT_hi,
                                                      const f16* __restrict__ WcT_lo,
                                                      const float* __restrict__ bc,
                                                      float* __restrict__ h1) {
  __shared__ float red[3][16][64];   // [wave-1][reg-idx][lane]
  int wave = threadIdx.x >> 6, lane = threadIdx.x & 63;
  int q = lane >> 4, r16 = lane & 15;
  int m0 = blockIdx.x * 16;
  int k0 = wave * 192;
  const float* xr = x + (size_t)(m0 + r16) * ND + k0;

  f32x4 acc[4];
#pragma unroll
  for (int nf = 0; nf < 4; nf++) acc[nf] = 0.f;

  for (int kk = 0; kk < 192; kk += 32) {
    int ko = kk + q * 8;
    float4 v0 = *(const float4*)(xr + ko);
    float4 v1 = *(const float4*)(xr + ko + 4);
    f16x8 a_hi, a_lo;
    float xv[8] = {v0.x, v0.y, v0.z, v0.w, v1.x, v1.y, v1.z, v1.w};
#pragma unroll
    for (int j = 0; j < 8; j++) {
      f16 h = (f16)xv[j];
      a_hi[j] = h;
      a_lo[j] = (f16)(xv[j] - (float)h);
    }
    f16x8 b_hi[4], b_lo[4];
#pragma unroll
    for (int nf = 0; nf < 4; nf++) {
      size_t off = (size_t)(nf * 16 + r16) * ND + k0 + ko;
      b_hi[nf] = *(const f16x8*)(WcT_hi + off);
      b_lo[nf] = *(const f16x8*)(WcT_lo + off);
    }
#pragma unroll
    for (int nf = 0; nf < 4; nf++) {
      acc[nf] = __builtin_amdgcn_mfma_f32_16x16x32_f16(a_hi, b_hi[nf], acc[nf], 0, 0, 0);
      acc[nf] = __builtin_amdgcn_mfma_f32_16x16x32_f16(a_lo, b_hi[nf], acc[nf], 0, 0, 0);
      acc[nf] = __builtin_amdgcn_mfma_f32_16x16x32_f16(a_hi, b_lo[nf], acc[nf], 0, 0, 0);
    }
  }

  if (wave > 0) {
#pragma unroll
    for (int nf = 0; nf < 4; nf++)
#pragma unroll
      for (int r = 0; r < 4; r++) red[wave - 1][nf * 4 + r][lane] = acc[nf][r];
  }
  __syncthreads();
  if (wave == 0) {
#pragma unroll
    for (int nf = 0; nf < 4; nf++) {
      int col = nf * 16 + r16;
      if (col < 60) {
        float bcv = bc[col];
#pragma unroll
        for (int r = 0; r < 4; r++) {
          float v = acc[nf][r] + red[0][nf * 4 + r][lane] + red[1][nf * 4 + r][lane]
                  + red[2][nf * 4 + r][lane] + bcv;
          h1[(size_t)(m0 + q * 4 + r) * 60 + col] = fmaxf(v, 0.f);
        }
      }
    }
  }
}

// ---------------- kernel 6: layers 2,3 + tanh + coord scatter; wave-per-row ----------------
__global__ void mlp_tail_kernel(const float* __restrict__ h1, const float* __restrict__ W2,
                                const float* __restrict__ b2, const float* __restrict__ W3,
                                const float* __restrict__ b3, float* __restrict__ coords) {
  int m = (blockIdx.x * 256 + threadIdx.x) >> 6;   // row
  int lane = threadIdx.x & 63;
  int cl = (lane < 60) ? lane : 59;
  const float* h = h1 + (size_t)m * 60;
  float acc = b2[cl];
  for (int j = 0; j < 60; j++) acc = fmaf(h[j], W2[j * 60 + cl], acc);
  float h2 = fmaxf(acc, 0.f);
  float p0 = (lane < 60) ? h2 * W3[cl * 2 + 0] : 0.f;
  float p1 = (lane < 60) ? h2 * W3[cl * 2 + 1] : 0.f;
#pragma unroll
  for (int o = 32; o > 0; o >>= 1) { p0 += __shfl_down(p0, o); p1 += __shfl_down(p1, o); }
  if (lane == 0) {
    float s0 = tanhf(p0 + b3[0]);
    float s1 = tanhf(p1 + b3[1]);
    int b = m / NS, s = m % NS;
    float* cb = coords + (size_t)b * (2 * NS);
    cb[(s >> 1) * 2 + (s & 1)] = s0;
    cb[(288 + (s >> 1)) * 2 + (s & 1)] = s1;
  }
}

// ---------------- kernel 7: bilinear sample + score + sigmoid*value; wave/point, 4/block ------
__global__ __launch_bounds__(256) void sample_kernel(const f16* __restrict__ qkv,
                                                     const float* __restrict__ coords,
                                                     float* __restrict__ out) {
  int wave = threadIdx.x >> 6, t = threadIdx.x & 63;
  int idx = blockIdx.x * 4 + wave;   // 0..18431
  int b = idx / NS, p = idx % NS;

  float gx = coords[(size_t)b * (2 * NS) + p * 2 + 0];
  float gy = coords[(size_t)b * (2 * NS) + p * 2 + 1];
  float ix = ((gx + 1.f) * (float)NG - 1.f) * 0.5f;
  float iy = ((gy + 1.f) * (float)NG - 1.f) * 0.5f;
  float x0f = floorf(ix), y0f = floorf(iy);
  float wx1 = ix - x0f, wx0 = 1.f - wx1;
  float wy1 = iy - y0f, wy0 = 1.f - wy1;
  int x0 = (int)x0f, y0 = (int)y0f, x1 = x0 + 1, y1 = y0 + 1;
  bool vx0 = (x0 >= 0) & (x0 <= NG - 1), vx1 = (x1 >= 0) & (x1 <= NG - 1);
  bool vy0 = (y0 >= 0) & (y0 <= NG - 1), vy1 = (y1 >= 0) & (y1 <= NG - 1);
  int cx0 = min(max(x0, 0), NG - 1), cx1 = min(max(x1, 0), NG - 1);
  int cy0 = min(max(y0, 0), NG - 1), cy1 = min(max(y1, 0), NG - 1);
  float w00 = wx0 * wy0 * ((vx0 && vy0) ? 1.f : 0.f);
  float w10 = wx1 * wy0 * ((vx1 && vy0) ? 1.f : 0.f);
  float w01 = wx0 * wy1 * ((vx0 && vy1) ? 1.f : 0.f);
  float w11 = wx1 * wy1 * ((vx1 && vy1) ? 1.f : 0.f);

  size_t base = (size_t)b * NS;
  const f16* r00 = qkv + (base + cy0 * NG + cx0) * N_TOT;
  const f16* r10 = qkv + (base + cy0 * NG + cx1) * N_TOT;
  const f16* r01 = qkv + (base + cy1 * NG + cx0) * N_TOT;
  const f16* r11 = qkv + (base + cy1 * NG + cx1) * N_TOT;
  const f16* qr  = qkv + (base + p) * N_TOT;

  int d0 = t * 12;
  float partial = 0.f;
  float outv[12];
#pragma unroll
  for (int ch = 0; ch < 3; ch++) {
    int d = d0 + ch * 4;
    f16x4 k00 = *(const f16x4*)(r00 + ND + d);
    f16x4 k10 = *(const f16x4*)(r10 + ND + d);
    f16x4 k01 = *(const f16x4*)(r01 + ND + d);
    f16x4 k11 = *(const f16x4*)(r11 + ND + d);
    f16x4 v00 = *(const f16x4*)(r00 + 2 * ND + d);
    f16x4 v10 = *(const f16x4*)(r10 + 2 * ND + d);
    f16x4 v01 = *(const f16x4*)(r01 + 2 * ND + d);
    f16x4 v11 = *(const f16x4*)(r11 + 2 * ND + d);
    f16x4 qv  = *(const f16x4*)(qr + d);
#pragma unroll
    for (int j = 0; j < 4; j++) {
      float sk = w00 * (float)k00[j] + w10 * (float)k10[j]
               + w01 * (float)k01[j] + w11 * (float)k11[j];
      float sv = w00 * (float)v00[j] + w10 * (float)v10[j]
               + w01 * (float)v01[j] + w11 * (float)v11[j];
      partial = fmaf((float)qv[j], sk, partial);
      outv[ch * 4 + j] = sv;
    }
  }
#pragma unroll
  for (int o = 32; o > 0; o >>= 1) partial += __shfl_down(partial, o);
  float score = __shfl(partial, 0);
  float sig = 1.f / (1.f + expf(-0.01f * score));
  float* orow = out + (size_t)(base + p) * ND;
#pragma unroll
  for (int ch = 0; ch < 3; ch++) {
    float4 st;
    st.x = sig * outv[ch * 4 + 0]; st.y = sig * outv[ch * 4 + 1];
    st.z = sig * outv[ch * 4 + 2]; st.w = sig * outv[ch * 4 + 3];
    *(float4*)(orow + d0 + ch * 4) = st;
  }
}

extern "C" void kernel_launch(void* const* d_in, const int* in_sizes, int n_in,
                              void* d_out, int out_size, void* d_ws, size_t ws_size,
                              hipStream_t stream) {
  const float* x  = (const float*)d_in[0];
  const float* Wq = (const float*)d_in[2];
  const float* bq = (const float*)d_in[3];
  const float* Wk = (const float*)d_in[4];
  const float* bk = (const float*)d_in[5];
  const float* Wv = (const float*)d_in[6];
  const float* bv = (const float*)d_in[7];
  const float* W1 = (const float*)d_in[8];
  const float* b1 = (const float*)d_in[9];
  const float* W2 = (const float*)d_in[10];
  const float* b2 = (const float*)d_in[11];
  const float* W3 = (const float*)d_in[12];
  const float* b3 = (const float*)d_in[13];
  float* out = (float*)d_out;

  char* ws = (char*)d_ws;
  f16*   xb     = (f16*)(ws);                       // 28,311,552
  f16*   WT     = (f16*)(ws + 28311552);            //  3,538,944
  f16*   qkv    = (f16*)(ws + 31850496);            // 84,934,656
  // pre-gemm scratch carved from qkv region (consumed by z1 BEFORE gemm writes qkv):
  f16*   WcT_hi = (f16*)(ws + 31850496);            //     98,304
  f16*   WcT_lo = (f16*)(ws + 31948800);            //     98,304
  float* bc     = (float*)(ws + 116969472);         //        256
  float* h1     = (float*)(ws + 116969728);         //  4,423,680
  float* coords = (float*)(ws + 121393408);         //    147,456 (total 121,540,864)

  cast_x_kernel<<<dim3(M_TOT * ND / 1024), dim3(256), 0, stream>>>(x, xb);
  cast_w_t_kernel<<<dim3(432), dim3(256), 0, stream>>>(Wq, Wk, Wv, WT);
  wcT_kernel<<<dim3(769), dim3(256), 0, stream>>>(Wq, Wk, bq, bk, W1, b1, WcT_hi, WcT_lo, bc);
  z1_mfma_kernel<<<dim3(M_TOT / 16), dim3(256), 0, stream>>>(x, WcT_hi, WcT_lo, bc, h1);
  gemm_kernel<<<dim3((M_TOT / 128) * (N_TOT / 128)), dim3(256), 0, stream>>>(xb, WT, bq, bk, bv, qkv);
  mlp_tail_kernel<<<dim3(M_TOT / 4), dim3(256), 0, stream>>>(h1, W2, b2, W3, b3, coords);
  sample_kernel<<<dim3(M_TOT / 4), dim3(256), 0, stream>>>(qkv, coords, out);
  (void)in_sizes; (void)n_in; (void)out_size; (void)ws_size;
}

// Round 7
// 349.511 us; speedup vs baseline: 1.1952x; 1.0175x over previous
//
#include <hip/hip_runtime.h>

typedef _Float16 f16;
typedef _Float16 f16x8 __attribute__((ext_vector_type(8)));
typedef _Float16 f16x4 __attribute__((ext_vector_type(4)));
typedef float f32x4 __attribute__((ext_vector_type(4)));

constexpr int NB = 32, NS = 576, ND = 768, NG = 24;
constexpr int M_TOT = NB * NS;   // 18432
constexpr int N_TOT = 3 * ND;    // 2304

// ---------------- kernel 1: build W_allT (N_TOT x ND) f16 via LDS tile transpose ----------------
__global__ __launch_bounds__(256) void cast_w_t_kernel(const float* __restrict__ Wq,
                                                       const float* __restrict__ Wk,
                                                       const float* __restrict__ Wv,
                                                       f16* __restrict__ WT) {
  __shared__ float tile[64][65];
  int bt = blockIdx.x;                 // 0..431
  int ntile = bt / 12, ktile = bt % 12;
  const float* src = (ntile < 12) ? Wq : ((ntile < 24) ? Wk : Wv);
  int n0 = (ntile % 12) * 64, k0 = ktile * 64;
  int cc = threadIdx.x & 63, rr = threadIdx.x >> 6;
#pragma unroll
  for (int i = 0; i < 16; i++) {
    int k = rr + i * 4;
    tile[cc][k] = src[(size_t)(k0 + k) * ND + n0 + cc];
  }
  __syncthreads();
#pragma unroll
  for (int i = 0; i < 16; i++) {
    int n = rr + i * 4;
    WT[(size_t)(ntile * 64 + n) * ND + k0 + cc] = (f16)tile[n][cc];
  }
}

// ---------------- kernel 2: WcT hi/lo, j-split x4 per block; bc in block 768 ----------------
__global__ __launch_bounds__(256) void wcT_kernel(const float* __restrict__ Wq,
                                                  const float* __restrict__ Wk,
                                                  const float* __restrict__ bq,
                                                  const float* __restrict__ bk,
                                                  const float* __restrict__ W1,
                                                  const float* __restrict__ b1,
                                                  f16* __restrict__ WcT_hi,
                                                  f16* __restrict__ WcT_lo,
                                                  float* __restrict__ bc) {
  if (blockIdx.x == 768) {
    int c = threadIdx.x;
    if (c < 60) {
      float acc = b1[c];
      for (int j = 0; j < ND; j++)
        acc += bq[j] * W1[j * 60 + c] + bk[j] * W1[(ND + j) * 60 + c];
      bc[c] = acc;
    }
    return;
  }
  __shared__ float part[4][64];
  int r = blockIdx.x;                       // 0..767
  int wave = threadIdx.x >> 6, lane = threadIdx.x & 63;
  int c = (lane < 60) ? lane : 59;
  const float* wq = Wq + (size_t)r * ND;
  const float* wk = Wk + (size_t)r * ND;
  float acc = 0.f;
  int j0 = wave * 192;
  for (int j = j0; j < j0 + 192; j++)
    acc += wq[j] * W1[j * 60 + c] + wk[j] * W1[(ND + j) * 60 + c];
  part[wave][lane] = acc;
  __syncthreads();
  if (wave == 0 && lane < 60) {
    float v = part[0][lane] + part[1][lane] + part[2][lane] + part[3][lane];
    f16 hi = (f16)v;
    WcT_hi[(size_t)lane * ND + r] = hi;
    WcT_lo[(size_t)lane * ND + r] = (f16)(v - (float)hi);
  }
}

// ---------------- kernel 3: fused z1 MFMA + x cast + MLP tail + coord scatter ----------------
// 1152 blocks x 16 rows; 4 waves = 4 K-quarters (192 each). Emits xb (f16 cast of x)
// during the K-loop; LDS combine -> h-tile; all waves run layers 2,3 + tanh + scatter.
__global__ __launch_bounds__(256) void z1_fused_kernel(const float* __restrict__ x,
                                                       const f16* __restrict__ WcT_hi,
                                                       const f16* __restrict__ WcT_lo,
                                                       const float* __restrict__ bc,
                                                       const float* __restrict__ W2,
                                                       const float* __restrict__ b2,
                                                       const float* __restrict__ W3,
                                                       const float* __restrict__ b3,
                                                       f16* __restrict__ xb,
                                                       float* __restrict__ coords) {
  __shared__ float red[3][16][64];   // [wave-1][reg-idx][lane]
  __shared__ float htile[16][60];    // relu(z1) tile for this block's 16 rows
  int wave = threadIdx.x >> 6, lane = threadIdx.x & 63;
  int q = lane >> 4, r16 = lane & 15;
  int m0 = blockIdx.x * 16;
  int k0 = wave * 192;
  const float* xr = x + (size_t)(m0 + r16) * ND + k0;
  f16* xbr = xb + (size_t)(m0 + r16) * ND + k0;

  f32x4 acc[4];
#pragma unroll
  for (int nf = 0; nf < 4; nf++) acc[nf] = 0.f;

  for (int kk = 0; kk < 192; kk += 32) {
    int ko = kk + q * 8;
    float4 v0 = *(const float4*)(xr + ko);
    float4 v1 = *(const float4*)(xr + ko + 4);
    f16x8 a_hi, a_lo;
    float xv[8] = {v0.x, v0.y, v0.z, v0.w, v1.x, v1.y, v1.z, v1.w};
#pragma unroll
    for (int j = 0; j < 8; j++) {
      f16 h = (f16)xv[j];
      a_hi[j] = h;
      a_lo[j] = (f16)(xv[j] - (float)h);
    }
    *(f16x8*)(xbr + ko) = a_hi;      // fused fp32->f16 cast of x
    f16x8 b_hi[4], b_lo[4];
#pragma unroll
    for (int nf = 0; nf < 4; nf++) {
      size_t off = (size_t)(nf * 16 + r16) * ND + k0 + ko;
      b_hi[nf] = *(const f16x8*)(WcT_hi + off);
      b_lo[nf] = *(const f16x8*)(WcT_lo + off);
    }
#pragma unroll
    for (int nf = 0; nf < 4; nf++) {
      acc[nf] = __builtin_amdgcn_mfma_f32_16x16x32_f16(a_hi, b_hi[nf], acc[nf], 0, 0, 0);
      acc[nf] = __builtin_amdgcn_mfma_f32_16x16x32_f16(a_lo, b_hi[nf], acc[nf], 0, 0, 0);
      acc[nf] = __builtin_amdgcn_mfma_f32_16x16x32_f16(a_hi, b_lo[nf], acc[nf], 0, 0, 0);
    }
  }

  if (wave > 0) {
#pragma unroll
    for (int nf = 0; nf < 4; nf++)
#pragma unroll
      for (int r = 0; r < 4; r++) red[wave - 1][nf * 4 + r][lane] = acc[nf][r];
  }
  __syncthreads();
  if (wave == 0) {
#pragma unroll
    for (int nf = 0; nf < 4; nf++) {
      int col = nf * 16 + r16;
      if (col < 60) {
        float bcv = bc[col];
#pragma unroll
        for (int r = 0; r < 4; r++) {
          float v = acc[nf][r] + red[0][nf * 4 + r][lane] + red[1][nf * 4 + r][lane]
                  + red[2][nf * 4 + r][lane] + bcv;
          htile[q * 4 + r][col] = fmaxf(v, 0.f);
        }
      }
    }
  }
  __syncthreads();

  // MLP tail: wave w -> rows 4w..4w+3; lane c<60 owns layer-2 column c.
  int c = (lane < 60) ? lane : 59;
  float b2v = b2[c];
  float w30 = W3[c * 2 + 0], w31 = W3[c * 2 + 1];
#pragma unroll
  for (int rr = 0; rr < 4; rr++) {
    int row = wave * 4 + rr;
    float acc2 = b2v;
    for (int j = 0; j < 60; j++) acc2 = fmaf(htile[row][j], W2[j * 60 + c], acc2);
    float h2 = fmaxf(acc2, 0.f);
    float p0 = (lane < 60) ? h2 * w30 : 0.f;
    float p1 = (lane < 60) ? h2 * w31 : 0.f;
#pragma unroll
    for (int o = 32; o > 0; o >>= 1) { p0 += __shfl_down(p0, o); p1 += __shfl_down(p1, o); }
    if (lane == 0) {
      float s0 = tanhf(p0 + b3[0]);
      float s1 = tanhf(p1 + b3[1]);
      int m = m0 + row;
      int b = m / NS, s = m % NS;
      float* cb = coords + (size_t)b * (2 * NS);
      cb[(s >> 1) * 2 + (s & 1)] = s0;
      cb[(288 + (s >> 1)) * 2 + (s & 1)] = s1;
    }
  }
}

// ---------------- kernel 4: GEMM qkv = x_f16 @ [Wq|Wk|Wv]_f16, BK=64 (unchanged control) ------
__device__ __forceinline__ void async_copy16(const f16* g, f16* l) {
  __builtin_amdgcn_global_load_lds((const __attribute__((address_space(1))) void*)g,
                                   (__attribute__((address_space(3))) void*)l, 16, 0, 0);
}

__global__ __launch_bounds__(256) void gemm_kernel(const f16* __restrict__ A,   // M_TOT x 768
                                                   const f16* __restrict__ Bt,  // 2304 x 768
                                                   const float* __restrict__ bq,
                                                   const float* __restrict__ bk,
                                                   const float* __restrict__ bv,
                                                   f16* __restrict__ C) {       // M_TOT x 2304
  constexpr int BM = 128, BK = 64;
  __shared__ __align__(16) f16 sA[BM * BK];   // 16 KB
  __shared__ __align__(16) f16 sB[BM * BK];   // 16 KB

  int bm = blockIdx.x % (M_TOT / BM);
  int bn = blockIdx.x / (M_TOT / BM);
  int tid = threadIdx.x;
  int wave = tid >> 6, lane = tid & 63;
  int wm = (wave >> 1) * 64, wn = (wave & 1) * 64;
  int m0 = bm * BM, n0 = bn * BM;

  int srow = tid >> 3;                          // 0..31
  int gchunk = ((tid & 7) ^ (srow & 7)) * 8;    // swizzled global chunk (elements)

  f32x4 acc[4][4];
#pragma unroll
  for (int i = 0; i < 4; i++)
#pragma unroll
    for (int j = 0; j < 4; j++) acc[i][j] = 0.f;

  int q = lane >> 4, r16 = lane & 15;

  for (int kk = 0; kk < ND; kk += BK) {
#pragma unroll
    for (int ps = 0; ps < 4; ps++) {
      async_copy16(A + (size_t)(m0 + ps * 32 + srow) * ND + kk + gchunk, sA + ps * 2048 + tid * 8);
      async_copy16(Bt + (size_t)(n0 + ps * 32 + srow) * ND + kk + gchunk, sB + ps * 2048 + tid * 8);
    }
    __syncthreads();

#pragma unroll
    for (int h = 0; h < 2; h++) {
      f16x8 aF[4], bF[4];
#pragma unroll
      for (int mt = 0; mt < 4; mt++) {
        int R = wm + mt * 16 + r16;
        aF[mt] = *(const f16x8*)(sA + R * 64 + (((h * 4 + q) ^ (R & 7)) * 8));
      }
#pragma unroll
      for (int nt = 0; nt < 4; nt++) {
        int R = wn + nt * 16 + r16;
        bF[nt] = *(const f16x8*)(sB + R * 64 + (((h * 4 + q) ^ (R & 7)) * 8));
      }
#pragma unroll
      for (int mt = 0; mt < 4; mt++)
#pragma unroll
        for (int nt = 0; nt < 4; nt++)   // swapped operands -> C^T register layout
          acc[mt][nt] = __builtin_amdgcn_mfma_f32_16x16x32_f16(bF[nt], aF[mt], acc[mt][nt], 0, 0, 0);
    }
    __syncthreads();
  }

#pragma unroll
  for (int mt = 0; mt < 4; mt++) {
    int gm = m0 + wm + mt * 16 + r16;
#pragma unroll
    for (int nt = 0; nt < 4; nt++) {
      int gn0 = n0 + wn + nt * 16 + q * 4;
      const float* bp = (gn0 < ND) ? (bq + gn0)
                      : ((gn0 < 2 * ND) ? (bk + gn0 - ND) : (bv + gn0 - 2 * ND));
      float4 bias = *(const float4*)bp;
      f16x4 o;
      o[0] = (f16)(acc[mt][nt][0] + bias.x);
      o[1] = (f16)(acc[mt][nt][1] + bias.y);
      o[2] = (f16)(acc[mt][nt][2] + bias.z);
      o[3] = (f16)(acc[mt][nt][3] + bias.w);
      *(f16x4*)(C + (size_t)gm * N_TOT + gn0) = o;
    }
  }
}

// ---------------- kernel 5: bilinear sample + score + sigmoid*value; wave/point, 4/block ------
__global__ __launch_bounds__(256) void sample_kernel(const f16* __restrict__ qkv,
                                                     const float* __restrict__ coords,
                                                     float* __restrict__ out) {
  int wave = threadIdx.x >> 6, t = threadIdx.x & 63;
  int idx = blockIdx.x * 4 + wave;   // 0..18431
  int b = idx / NS, p = idx % NS;

  float gx = coords[(size_t)b * (2 * NS) + p * 2 + 0];
  float gy = coords[(size_t)b * (2 * NS) + p * 2 + 1];
  float ix = ((gx + 1.f) * (float)NG - 1.f) * 0.5f;
  float iy = ((gy + 1.f) * (float)NG - 1.f) * 0.5f;
  float x0f = floorf(ix), y0f = floorf(iy);
  float wx1 = ix - x0f, wx0 = 1.f - wx1;
  float wy1 = iy - y0f, wy0 = 1.f - wy1;
  int x0 = (int)x0f, y0 = (int)y0f, x1 = x0 + 1, y1 = y0 + 1;
  bool vx0 = (x0 >= 0) & (x0 <= NG - 1), vx1 = (x1 >= 0) & (x1 <= NG - 1);
  bool vy0 = (y0 >= 0) & (y0 <= NG - 1), vy1 = (y1 >= 0) & (y1 <= NG - 1);
  int cx0 = min(max(x0, 0), NG - 1), cx1 = min(max(x1, 0), NG - 1);
  int cy0 = min(max(y0, 0), NG - 1), cy1 = min(max(y1, 0), NG - 1);
  float w00 = wx0 * wy0 * ((vx0 && vy0) ? 1.f : 0.f);
  float w10 = wx1 * wy0 * ((vx1 && vy0) ? 1.f : 0.f);
  float w01 = wx0 * wy1 * ((vx0 && vy1) ? 1.f : 0.f);
  float w11 = wx1 * wy1 * ((vx1 && vy1) ? 1.f : 0.f);

  size_t base = (size_t)b * NS;
  const f16* r00 = qkv + (base + cy0 * NG + cx0) * N_TOT;
  const f16* r10 = qkv + (base + cy0 * NG + cx1) * N_TOT;
  const f16* r01 = qkv + (base + cy1 * NG + cx0) * N_TOT;
  const f16* r11 = qkv + (base + cy1 * NG + cx1) * N_TOT;
  const f16* qr  = qkv + (base + p) * N_TOT;

  int d0 = t * 12;
  float partial = 0.f;
  float outv[12];
#pragma unroll
  for (int ch = 0; ch < 3; ch++) {
    int d = d0 + ch * 4;
    f16x4 k00 = *(const f16x4*)(r00 + ND + d);
    f16x4 k10 = *(const f16x4*)(r10 + ND + d);
    f16x4 k01 = *(const f16x4*)(r01 + ND + d);
    f16x4 k11 = *(const f16x4*)(r11 + ND + d);
    f16x4 v00 = *(const f16x4*)(r00 + 2 * ND + d);
    f16x4 v10 = *(const f16x4*)(r10 + 2 * ND + d);
    f16x4 v01 = *(const f16x4*)(r01 + 2 * ND + d);
    f16x4 v11 = *(const f16x4*)(r11 + 2 * ND + d);
    f16x4 qv  = *(const f16x4*)(qr + d);
#pragma unroll
    for (int j = 0; j < 4; j++) {
      float sk = w00 * (float)k00[j] + w10 * (float)k10[j]
               + w01 * (float)k01[j] + w11 * (float)k11[j];
      float sv = w00 * (float)v00[j] + w10 * (float)v10[j]
               + w01 * (float)v01[j] + w11 * (float)v11[j];
      partial = fmaf((float)qv[j], sk, partial);
      outv[ch * 4 + j] = sv;
    }
  }
#pragma unroll
  for (int o = 32; o > 0; o >>= 1) partial += __shfl_down(partial, o);
  float score = __shfl(partial, 0);
  float sig = 1.f / (1.f + expf(-0.01f * score));
  float* orow = out + (size_t)(base + p) * ND;
#pragma unroll
  for (int ch = 0; ch < 3; ch++) {
    float4 st;
    st.x = sig * outv[ch * 4 + 0]; st.y = sig * outv[ch * 4 + 1];
    st.z = sig * outv[ch * 4 + 2]; st.w = sig * outv[ch * 4 + 3];
    *(float4*)(orow + d0 + ch * 4) = st;
  }
}

extern "C" void kernel_launch(void* const* d_in, const int* in_sizes, int n_in,
                              void* d_out, int out_size, void* d_ws, size_t ws_size,
                              hipStream_t stream) {
  const float* x  = (const float*)d_in[0];
  const float* Wq = (const float*)d_in[2];
  const float* bq = (const float*)d_in[3];
  const float* Wk = (const float*)d_in[4];
  const float* bk = (const float*)d_in[5];
  const float* Wv = (const float*)d_in[6];
  const float* bv = (const float*)d_in[7];
  const float* W1 = (const float*)d_in[8];
  const float* b1 = (const float*)d_in[9];
  const float* W2 = (const float*)d_in[10];
  const float* b2 = (const float*)d_in[11];
  const float* W3 = (const float*)d_in[12];
  const float* b3 = (const float*)d_in[13];
  float* out = (float*)d_out;

  char* ws = (char*)d_ws;
  f16*   xb     = (f16*)(ws);                       // 28,311,552
  f16*   WT     = (f16*)(ws + 28311552);            //  3,538,944
  f16*   qkv    = (f16*)(ws + 31850496);            // 84,934,656
  // pre-gemm scratch carved from qkv region (consumed by z1 BEFORE gemm writes qkv):
  f16*   WcT_hi = (f16*)(ws + 31850496);            //     98,304
  f16*   WcT_lo = (f16*)(ws + 31948800);            //     98,304
  float* bc     = (float*)(ws + 116969472);         //        256
  float* coords = (float*)(ws + 121393408);         //    147,456 (total 121,540,864)

  cast_w_t_kernel<<<dim3(432), dim3(256), 0, stream>>>(Wq, Wk, Wv, WT);
  wcT_kernel<<<dim3(769), dim3(256), 0, stream>>>(Wq, Wk, bq, bk, W1, b1, WcT_hi, WcT_lo, bc);
  z1_fused_kernel<<<dim3(M_TOT / 16), dim3(256), 0, stream>>>(x, WcT_hi, WcT_lo, bc,
                                                              W2, b2, W3, b3, xb, coords);
  gemm_kernel<<<dim3((M_TOT / 128) * (N_TOT / 128)), dim3(256), 0, stream>>>(xb, WT, bq, bk, bv, qkv);
  sample_kernel<<<dim3(M_TOT / 4), dim3(256), 0, stream>>>(qkv, coords, out);
  (void)in_sizes; (void)n_in; (void)out_size; (void)ws_size;
}

// Round 8
// 349.041 us; speedup vs baseline: 1.1968x; 1.0013x over previous
//
#include <hip/hip_runtime.h>

typedef _Float16 f16;
typedef _Float16 f16x8 __attribute__((ext_vector_type(8)));
typedef _Float16 f16x4 __attribute__((ext_vector_type(4)));
typedef float f32x4 __attribute__((ext_vector_type(4)));
typedef float f32x16 __attribute__((ext_vector_type(16)));

constexpr int NB = 32, NS = 576, ND = 768, NG = 24;
constexpr int M_TOT = NB * NS;   // 18432
constexpr int N_TOT = 3 * ND;    // 2304

// ---------------- kernel 1: build W_allT (N_TOT x ND) f16 via LDS tile transpose ----------------
__global__ __launch_bounds__(256) void cast_w_t_kernel(const float* __restrict__ Wq,
                                                       const float* __restrict__ Wk,
                                                       const float* __restrict__ Wv,
                                                       f16* __restrict__ WT) {
  __shared__ float tile[64][65];
  int bt = blockIdx.x;                 // 0..431
  int ntile = bt / 12, ktile = bt % 12;
  const float* src = (ntile < 12) ? Wq : ((ntile < 24) ? Wk : Wv);
  int n0 = (ntile % 12) * 64, k0 = ktile * 64;
  int cc = threadIdx.x & 63, rr = threadIdx.x >> 6;
#pragma unroll
  for (int i = 0; i < 16; i++) {
    int k = rr + i * 4;
    tile[cc][k] = src[(size_t)(k0 + k) * ND + n0 + cc];
  }
  __syncthreads();
#pragma unroll
  for (int i = 0; i < 16; i++) {
    int n = rr + i * 4;
    WT[(size_t)(ntile * 64 + n) * ND + k0 + cc] = (f16)tile[n][cc];
  }
}

// ---------------- kernel 2: WcT hi/lo, j-split x4 per block; bc in block 768 ----------------
__global__ __launch_bounds__(256) void wcT_kernel(const float* __restrict__ Wq,
                                                  const float* __restrict__ Wk,
                                                  const float* __restrict__ bq,
                                                  const float* __restrict__ bk,
                                                  const float* __restrict__ W1,
                                                  const float* __restrict__ b1,
                                                  f16* __restrict__ WcT_hi,
                                                  f16* __restrict__ WcT_lo,
                                                  float* __restrict__ bc) {
  if (blockIdx.x == 768) {
    int c = threadIdx.x;
    if (c < 60) {
      float acc = b1[c];
      for (int j = 0; j < ND; j++)
        acc += bq[j] * W1[j * 60 + c] + bk[j] * W1[(ND + j) * 60 + c];
      bc[c] = acc;
    }
    return;
  }
  __shared__ float part[4][64];
  int r = blockIdx.x;                       // 0..767
  int wave = threadIdx.x >> 6, lane = threadIdx.x & 63;
  int c = (lane < 60) ? lane : 59;
  const float* wq = Wq + (size_t)r * ND;
  const float* wk = Wk + (size_t)r * ND;
  float acc = 0.f;
  int j0 = wave * 192;
  for (int j = j0; j < j0 + 192; j++)
    acc += wq[j] * W1[j * 60 + c] + wk[j] * W1[(ND + j) * 60 + c];
  part[wave][lane] = acc;
  __syncthreads();
  if (wave == 0 && lane < 60) {
    float v = part[0][lane] + part[1][lane] + part[2][lane] + part[3][lane];
    f16 hi = (f16)v;
    WcT_hi[(size_t)lane * ND + r] = hi;
    WcT_lo[(size_t)lane * ND + r] = (f16)(v - (float)hi);
  }
}

// ---------------- kernel 3: fused z1 MFMA + x cast + MLP tail + coord scatter ----------------
__global__ __launch_bounds__(256) void z1_fused_kernel(const float* __restrict__ x,
                                                       const f16* __restrict__ WcT_hi,
                                                       const f16* __restrict__ WcT_lo,
                                                       const float* __restrict__ bc,
                                                       const float* __restrict__ W2,
                                                       const float* __restrict__ b2,
                                                       const float* __restrict__ W3,
                                                       const float* __restrict__ b3,
                                                       f16* __restrict__ xb,
                                                       float* __restrict__ coords) {
  __shared__ float red[3][16][64];   // [wave-1][reg-idx][lane]
  __shared__ float htile[16][60];    // relu(z1) tile for this block's 16 rows
  int wave = threadIdx.x >> 6, lane = threadIdx.x & 63;
  int q = lane >> 4, r16 = lane & 15;
  int m0 = blockIdx.x * 16;
  int k0 = wave * 192;
  const float* xr = x + (size_t)(m0 + r16) * ND + k0;
  f16* xbr = xb + (size_t)(m0 + r16) * ND + k0;

  f32x4 acc[4];
#pragma unroll
  for (int nf = 0; nf < 4; nf++) acc[nf] = 0.f;

  for (int kk = 0; kk < 192; kk += 32) {
    int ko = kk + q * 8;
    float4 v0 = *(const float4*)(xr + ko);
    float4 v1 = *(const float4*)(xr + ko + 4);
    f16x8 a_hi, a_lo;
    float xv[8] = {v0.x, v0.y, v0.z, v0.w, v1.x, v1.y, v1.z, v1.w};
#pragma unroll
    for (int j = 0; j < 8; j++) {
      f16 h = (f16)xv[j];
      a_hi[j] = h;
      a_lo[j] = (f16)(xv[j] - (float)h);
    }
    *(f16x8*)(xbr + ko) = a_hi;      // fused fp32->f16 cast of x
    f16x8 b_hi[4], b_lo[4];
#pragma unroll
    for (int nf = 0; nf < 4; nf++) {
      size_t off = (size_t)(nf * 16 + r16) * ND + k0 + ko;
      b_hi[nf] = *(const f16x8*)(WcT_hi + off);
      b_lo[nf] = *(const f16x8*)(WcT_lo + off);
    }
#pragma unroll
    for (int nf = 0; nf < 4; nf++) {
      acc[nf] = __builtin_amdgcn_mfma_f32_16x16x32_f16(a_hi, b_hi[nf], acc[nf], 0, 0, 0);
      acc[nf] = __builtin_amdgcn_mfma_f32_16x16x32_f16(a_lo, b_hi[nf], acc[nf], 0, 0, 0);
      acc[nf] = __builtin_amdgcn_mfma_f32_16x16x32_f16(a_hi, b_lo[nf], acc[nf], 0, 0, 0);
    }
  }

  if (wave > 0) {
#pragma unroll
    for (int nf = 0; nf < 4; nf++)
#pragma unroll
      for (int r = 0; r < 4; r++) red[wave - 1][nf * 4 + r][lane] = acc[nf][r];
  }
  __syncthreads();
  if (wave == 0) {
#pragma unroll
    for (int nf = 0; nf < 4; nf++) {
      int col = nf * 16 + r16;
      if (col < 60) {
        float bcv = bc[col];
#pragma unroll
        for (int r = 0; r < 4; r++) {
          float v = acc[nf][r] + red[0][nf * 4 + r][lane] + red[1][nf * 4 + r][lane]
                  + red[2][nf * 4 + r][lane] + bcv;
          htile[q * 4 + r][col] = fmaxf(v, 0.f);
        }
      }
    }
  }
  __syncthreads();

  // MLP tail: wave w -> rows 4w..4w+3; lane c<60 owns layer-2 column c.
  int c = (lane < 60) ? lane : 59;
  float b2v = b2[c];
  float w30 = W3[c * 2 + 0], w31 = W3[c * 2 + 1];
#pragma unroll
  for (int rr = 0; rr < 4; rr++) {
    int row = wave * 4 + rr;
    float acc2 = b2v;
    for (int j = 0; j < 60; j++) acc2 = fmaf(htile[row][j], W2[j * 60 + c], acc2);
    float h2 = fmaxf(acc2, 0.f);
    float p0 = (lane < 60) ? h2 * w30 : 0.f;
    float p1 = (lane < 60) ? h2 * w31 : 0.f;
#pragma unroll
    for (int o = 32; o > 0; o >>= 1) { p0 += __shfl_down(p0, o); p1 += __shfl_down(p1, o); }
    if (lane == 0) {
      float s0 = tanhf(p0 + b3[0]);
      float s1 = tanhf(p1 + b3[1]);
      int m = m0 + row;
      int b = m / NS, s = m % NS;
      float* cb = coords + (size_t)b * (2 * NS);
      cb[(s >> 1) * 2 + (s & 1)] = s0;
      cb[(288 + (s >> 1)) * 2 + (s & 1)] = s1;
    }
  }
}

// ---------------- kernel 4: GEMM qkv = x_f16 @ [Wq|Wk|Wv]_f16, BK=64, 32x32x16 MFMA ----------
__device__ __forceinline__ void async_copy16(const f16* g, f16* l) {
  __builtin_amdgcn_global_load_lds((const __attribute__((address_space(1))) void*)g,
                                   (__attribute__((address_space(3))) void*)l, 16, 0, 0);
}

__global__ __launch_bounds__(256) void gemm_kernel(const f16* __restrict__ A,   // M_TOT x 768
                                                   const f16* __restrict__ Bt,  // 2304 x 768
                                                   const float* __restrict__ bq,
                                                   const float* __restrict__ bk,
                                                   const float* __restrict__ bv,
                                                   f16* __restrict__ C) {       // M_TOT x 2304
  constexpr int BM = 128, BK = 64;
  __shared__ __align__(16) f16 sA[BM * BK];   // 16 KB
  __shared__ __align__(16) f16 sB[BM * BK];   // 16 KB

  int bm = blockIdx.x % (M_TOT / BM);
  int bn = blockIdx.x / (M_TOT / BM);
  int tid = threadIdx.x;
  int wave = tid >> 6, lane = tid & 63;
  int wm = (wave >> 1) * 64, wn = (wave & 1) * 64;
  int m0 = bm * BM, n0 = bn * BM;

  int srow = tid >> 3;                          // 0..31
  int gchunk = ((tid & 7) ^ (srow & 7)) * 8;    // swizzled global chunk (elements)

  f32x16 acc[2][2];
#pragma unroll
  for (int i = 0; i < 2; i++)
#pragma unroll
    for (int j = 0; j < 2; j++) acc[i][j] = 0.f;

  int r32 = lane & 31, q2 = lane >> 5;          // 32x32 frag: row = lane&31, k-half = lane>>5

  for (int kk = 0; kk < ND; kk += BK) {
#pragma unroll
    for (int ps = 0; ps < 4; ps++) {
      async_copy16(A + (size_t)(m0 + ps * 32 + srow) * ND + kk + gchunk, sA + ps * 2048 + tid * 8);
      async_copy16(Bt + (size_t)(n0 + ps * 32 + srow) * ND + kk + gchunk, sB + ps * 2048 + tid * 8);
    }
    __syncthreads();

#pragma unroll
    for (int ks = 0; ks < 4; ks++) {            // 4 K-steps of 16
      f16x8 aF[2], bF[2];
#pragma unroll
      for (int mt = 0; mt < 2; mt++) {
        int R = wm + mt * 32 + r32;
        aF[mt] = *(const f16x8*)(sA + R * 64 + (((ks * 2 + q2) ^ (R & 7)) * 8));
      }
#pragma unroll
      for (int nt = 0; nt < 2; nt++) {
        int R = wn + nt * 32 + r32;
        bF[nt] = *(const f16x8*)(sB + R * 64 + (((ks * 2 + q2) ^ (R & 7)) * 8));
      }
#pragma unroll
      for (int mt = 0; mt < 2; mt++)
#pragma unroll
        for (int nt = 0; nt < 2; nt++)   // swapped operands -> C^T register layout
          acc[mt][nt] = __builtin_amdgcn_mfma_f32_32x32x16_f16(bF[nt], aF[mt], acc[mt][nt], 0, 0, 0);
    }
    __syncthreads();
  }

#pragma unroll
  for (int mt = 0; mt < 2; mt++) {
    int gm = m0 + wm + mt * 32 + r32;
#pragma unroll
    for (int nt = 0; nt < 2; nt++) {
#pragma unroll
      for (int g = 0; g < 4; g++) {
        int gn0 = n0 + wn + nt * 32 + 8 * g + 4 * q2;
        const float* bp = (gn0 < ND) ? (bq + gn0)
                        : ((gn0 < 2 * ND) ? (bk + gn0 - ND) : (bv + gn0 - 2 * ND));
        float4 bias = *(const float4*)bp;
        f16x4 o;
        o[0] = (f16)(acc[mt][nt][4 * g + 0] + bias.x);
        o[1] = (f16)(acc[mt][nt][4 * g + 1] + bias.y);
        o[2] = (f16)(acc[mt][nt][4 * g + 2] + bias.z);
        o[3] = (f16)(acc[mt][nt][4 * g + 3] + bias.w);
        *(f16x4*)(C + (size_t)gm * N_TOT + gn0) = o;
      }
    }
  }
}

// ---------------- kernel 5: bilinear sample + score + sigmoid*value; XCD-swizzled ------------
// blk&7 -> XCD; each XCD handles 4 batches (21 MB qkv working set vs 85 MB unswizzled).
__global__ __launch_bounds__(256) void sample_kernel(const f16* __restrict__ qkv,
                                                     const float* __restrict__ coords,
                                                     float* __restrict__ out) {
  int wave = threadIdx.x >> 6, t = threadIdx.x & 63;
  int x8 = blockIdx.x & 7;           // XCD heuristic (blockIdx % 8)
  int i = blockIdx.x >> 3;           // 0..575
  int b = x8 * 4 + (i / 144);        // batch
  int p = (i % 144) * 4 + wave;      // point in batch

  float gx = coords[(size_t)b * (2 * NS) + p * 2 + 0];
  float gy = coords[(size_t)b * (2 * NS) + p * 2 + 1];
  float ix = ((gx + 1.f) * (float)NG - 1.f) * 0.5f;
  float iy = ((gy + 1.f) * (float)NG - 1.f) * 0.5f;
  float x0f = floorf(ix), y0f = floorf(iy);
  float wx1 = ix - x0f, wx0 = 1.f - wx1;
  float wy1 = iy - y0f, wy0 = 1.f - wy1;
  int x0 = (int)x0f, y0 = (int)y0f, x1 = x0 + 1, y1 = y0 + 1;
  bool vx0 = (x0 >= 0) & (x0 <= NG - 1), vx1 = (x1 >= 0) & (x1 <= NG - 1);
  bool vy0 = (y0 >= 0) & (y0 <= NG - 1), vy1 = (y1 >= 0) & (y1 <= NG - 1);
  int cx0 = min(max(x0, 0), NG - 1), cx1 = min(max(x1, 0), NG - 1);
  int cy0 = min(max(y0, 0), NG - 1), cy1 = min(max(y1, 0), NG - 1);
  float w00 = wx0 * wy0 * ((vx0 && vy0) ? 1.f : 0.f);
  float w10 = wx1 * wy0 * ((vx1 && vy0) ? 1.f : 0.f);
  float w01 = wx0 * wy1 * ((vx0 && vy1) ? 1.f : 0.f);
  float w11 = wx1 * wy1 * ((vx1 && vy1) ? 1.f : 0.f);

  size_t base = (size_t)b * NS;
  const f16* r00 = qkv + (base + cy0 * NG + cx0) * N_TOT;
  const f16* r10 = qkv + (base + cy0 * NG + cx1) * N_TOT;
  const f16* r01 = qkv + (base + cy1 * NG + cx0) * N_TOT;
  const f16* r11 = qkv + (base + cy1 * NG + cx1) * N_TOT;
  const f16* qr  = qkv + (base + p) * N_TOT;

  int d0 = t * 12;
  float partial = 0.f;
  float outv[12];
#pragma unroll
  for (int ch = 0; ch < 3; ch++) {
    int d = d0 + ch * 4;
    f16x4 k00 = *(const f16x4*)(r00 + ND + d);
    f16x4 k10 = *(const f16x4*)(r10 + ND + d);
    f16x4 k01 = *(const f16x4*)(r01 + ND + d);
    f16x4 k11 = *(const f16x4*)(r11 + ND + d);
    f16x4 v00 = *(const f16x4*)(r00 + 2 * ND + d);
    f16x4 v10 = *(const f16x4*)(r10 + 2 * ND + d);
    f16x4 v01 = *(const f16x4*)(r01 + 2 * ND + d);
    f16x4 v11 = *(const f16x4*)(r11 + 2 * ND + d);
    f16x4 qv  = *(const f16x4*)(qr + d);
#pragma unroll
    for (int j = 0; j < 4; j++) {
      float sk = w00 * (float)k00[j] + w10 * (float)k10[j]
               + w01 * (float)k01[j] + w11 * (float)k11[j];
      float sv = w00 * (float)v00[j] + w10 * (float)v10[j]
               + w01 * (float)v01[j] + w11 * (float)v11[j];
      partial = fmaf((float)qv[j], sk, partial);
      outv[ch * 4 + j] = sv;
    }
  }
#pragma unroll
  for (int o = 32; o > 0; o >>= 1) partial += __shfl_down(partial, o);
  float score = __shfl(partial, 0);
  float sig = 1.f / (1.f + expf(-0.01f * score));
  float* orow = out + (size_t)(base + p) * ND;
#pragma unroll
  for (int ch = 0; ch < 3; ch++) {
    float4 st;
    st.x = sig * outv[ch * 4 + 0]; st.y = sig * outv[ch * 4 + 1];
    st.z = sig * outv[ch * 4 + 2]; st.w = sig * outv[ch * 4 + 3];
    *(float4*)(orow + d0 + ch * 4) = st;
  }
}

extern "C" void kernel_launch(void* const* d_in, const int* in_sizes, int n_in,
                              void* d_out, int out_size, void* d_ws, size_t ws_size,
                              hipStream_t stream) {
  const float* x  = (const float*)d_in[0];
  const float* Wq = (const float*)d_in[2];
  const float* bq = (const float*)d_in[3];
  const float* Wk = (const float*)d_in[4];
  const float* bk = (const float*)d_in[5];
  const float* Wv = (const float*)d_in[6];
  const float* bv = (const float*)d_in[7];
  const float* W1 = (const float*)d_in[8];
  const float* b1 = (const float*)d_in[9];
  const float* W2 = (const float*)d_in[10];
  const float* b2 = (const float*)d_in[11];
  const float* W3 = (const float*)d_in[12];
  const float* b3 = (const float*)d_in[13];
  float* out = (float*)d_out;

  char* ws = (char*)d_ws;
  f16*   xb     = (f16*)(ws);                       // 28,311,552
  f16*   WT     = (f16*)(ws + 28311552);            //  3,538,944
  f16*   qkv    = (f16*)(ws + 31850496);            // 84,934,656
  // pre-gemm scratch carved from qkv region (consumed by z1 BEFORE gemm writes qkv):
  f16*   WcT_hi = (f16*)(ws + 31850496);            //     98,304
  f16*   WcT_lo = (f16*)(ws + 31948800);            //     98,304
  float* bc     = (float*)(ws + 116969472);         //        256
  float* coords = (float*)(ws + 121393408);         //    147,456 (total 121,540,864)

  cast_w_t_kernel<<<dim3(432), dim3(256), 0, stream>>>(Wq, Wk, Wv, WT);
  wcT_kernel<<<dim3(769), dim3(256), 0, stream>>>(Wq, Wk, bq, bk, W1, b1, WcT_hi, WcT_lo, bc);
  z1_fused_kernel<<<dim3(M_TOT / 16), dim3(256), 0, stream>>>(x, WcT_hi, WcT_lo, bc,
                                                              W2, b2, W3, b3, xb, coords);
  gemm_kernel<<<dim3((M_TOT / 128) * (N_TOT / 128)), dim3(256), 0, stream>>>(xb, WT, bq, bk, bv, qkv);
  sample_kernel<<<dim3(M_TOT / 4), dim3(256), 0, stream>>>(qkv, coords, out);
  (void)in_sizes; (void)n_in; (void)out_size; (void)ws_size;
}